// Round 1
// baseline (79.085 us; speedup 1.0000x reference)
//
#include <hip/hip_runtime.h>
#include <hip/hip_bf16.h>

// IncidenceConvolution: reference collapses algebraically.
// weight(x) = A*x + C (affine MLP, no activations), so
// out[row] = A * (sum x^2) + C * (sum x) with x = inc/S1:
//          = A * S2 / S1^2 + C            (S1 = sum inc, S2 = sum inc^2)
// => pure per-row reduction over the 16 MiB input. HBM-read bound.

#define HID 32
#define L_LEN 2048
#define BLOCK 256

__global__ __launch_bounds__(BLOCK) void inc_conv_kernel(
    const float* __restrict__ inc,
    const float* __restrict__ w1, const float* __restrict__ b1,
    const float* __restrict__ w2, const float* __restrict__ b2,
    const float* __restrict__ w3, const float* __restrict__ b3,
    const float* __restrict__ w4, const float* __restrict__ b4,
    float* __restrict__ out)
{
    const int row = blockIdx.x;          // 0 .. B*F-1 (2048)
    const int tid = threadIdx.x;         // 0 .. 255

    __shared__ float s_v2[HID];
    __shared__ float s_c2[HID];
    __shared__ float s_partial[8];       // 4 waves x {s1, s2}
    __shared__ float s_AC[2];

    // ---------------- per-row S1, S2 ----------------
    const float4* p = (const float4*)(inc + (size_t)row * L_LEN);
    float s1 = 0.f, s2 = 0.f;
#pragma unroll
    for (int i = 0; i < L_LEN / (4 * BLOCK); ++i) {
        float4 v = p[tid + i * BLOCK];
        s1 += (v.x + v.y) + (v.z + v.w);
        s2 += (v.x * v.x + v.y * v.y) + (v.z * v.z + v.w * v.w);
    }
#pragma unroll
    for (int off = 32; off > 0; off >>= 1) {
        s1 += __shfl_down(s1, off, 64);
        s2 += __shfl_down(s2, off, 64);
    }
    const int wave = tid >> 6;
    const int lane = tid & 63;
    if (lane == 0) {
        s_partial[wave * 2 + 0] = s1;
        s_partial[wave * 2 + 1] = s2;
    }

    // ---------------- fold MLP weights into A, C (32 lanes, redundant per block;
    // w2/w3 are 8 KB broadcast reads, L1/L2-cached) ----------------
    if (tid < HID) {
        const int k = tid;
        float v2 = 0.f, c2 = 0.f;
#pragma unroll
        for (int h = 0; h < HID; ++h) {
            const float w = w2[h * HID + k];
            v2 += w1[h] * w;
            c2 += b1[h] * w;
        }
        s_v2[k] = v2;
        s_c2[k] = c2 + b2[k];
    }
    __syncthreads();
    if (tid < HID) {
        const int k = tid;
        float v3 = 0.f, c3 = 0.f;
#pragma unroll
        for (int h = 0; h < HID; ++h) {
            const float w = w3[h * HID + k];
            v3 += s_v2[h] * w;
            c3 += s_c2[h] * w;
        }
        const float wk = w4[k];
        float a = v3 * wk;
        float c = (c3 + b3[k]) * wk;
#pragma unroll
        for (int off = 16; off > 0; off >>= 1) {
            a += __shfl_down(a, off, 64);
            c += __shfl_down(c, off, 64);
        }
        if (k == 0) {
            s_AC[0] = a;              // A
            s_AC[1] = c + b4[0];      // C
        }
    }
    __syncthreads();

    if (tid == 0) {
        const float S1 = (s_partial[0] + s_partial[2]) + (s_partial[4] + s_partial[6]);
        const float S2 = (s_partial[1] + s_partial[3]) + (s_partial[5] + s_partial[7]);
        out[row] = s_AC[0] * S2 / (S1 * S1) + s_AC[1];
    }
}

extern "C" void kernel_launch(void* const* d_in, const int* in_sizes, int n_in,
                              void* d_out, int out_size, void* d_ws, size_t ws_size,
                              hipStream_t stream) {
    const float* inc = (const float*)d_in[0];   // [64, 32, 2048]
    const float* w1  = (const float*)d_in[1];   // [32]
    const float* b1  = (const float*)d_in[2];   // [32]
    const float* w2  = (const float*)d_in[3];   // [32, 32]
    const float* b2  = (const float*)d_in[4];   // [32]
    const float* w3  = (const float*)d_in[5];   // [32, 32]
    const float* b3  = (const float*)d_in[6];   // [32]
    const float* w4  = (const float*)d_in[7];   // [32]
    const float* b4  = (const float*)d_in[8];   // scalar
    float* out = (float*)d_out;                 // [64, 32] = 2048

    const int rows = out_size;                  // 2048
    inc_conv_kernel<<<rows, BLOCK, 0, stream>>>(inc, w1, b1, w2, b2, w3, b3, w4, b4, out);
}

// Round 2
// 77.583 us; speedup vs baseline: 1.0194x; 1.0194x over previous
//
#include <hip/hip_runtime.h>
#include <hip/hip_bf16.h>

// IncidenceConvolution: the reference is an affine (no-activation) MLP on
// x = inc/S1, so weight(x) = A*x + C with A,C foldable from weights alone:
//   out[row] = A * S2 / S1^2 + C     (S1 = sum inc, S2 = sum inc^2)
// Kernel 1 (one tiny block): fold weights -> A, C in d_ws.
// Kernel 2 (one block/row): pure streaming sum / sum-of-squares reduction.

#define HID 32
#define L_LEN 2048
#define BLOCK 256

__global__ __launch_bounds__(64) void fold_kernel(
    const float* __restrict__ w1, const float* __restrict__ b1,
    const float* __restrict__ w2, const float* __restrict__ b2,
    const float* __restrict__ w3, const float* __restrict__ b3,
    const float* __restrict__ w4, const float* __restrict__ b4,
    float* __restrict__ ws)
{
    __shared__ float s_v2[HID];
    __shared__ float s_c2[HID];
    const int k = threadIdx.x;

    if (k < HID) {
        float v2 = 0.f, c2 = 0.f;
#pragma unroll
        for (int h = 0; h < HID; ++h) {
            const float w = w2[h * HID + k];
            v2 += w1[h] * w;
            c2 += b1[h] * w;
        }
        s_v2[k] = v2;
        s_c2[k] = c2 + b2[k];
    }
    __syncthreads();
    if (k < HID) {
        float v3 = 0.f, c3 = 0.f;
#pragma unroll
        for (int h = 0; h < HID; ++h) {
            const float w = w3[h * HID + k];
            v3 += s_v2[h] * w;
            c3 += s_c2[h] * w;
        }
        const float wk = w4[k];
        float a = v3 * wk;
        float c = (c3 + b3[k]) * wk;
#pragma unroll
        for (int off = 16; off > 0; off >>= 1) {
            a += __shfl_down(a, off, 64);
            c += __shfl_down(c, off, 64);
        }
        if (k == 0) {
            ws[0] = a;              // A
            ws[1] = c + b4[0];      // C
        }
    }
}

__global__ __launch_bounds__(BLOCK) void reduce_kernel(
    const float* __restrict__ inc,
    const float* __restrict__ ws,
    float* __restrict__ out)
{
    const int row = blockIdx.x;          // 0 .. 2047
    const int tid = threadIdx.x;         // 0 .. 255

    __shared__ float s_partial[8];       // 4 waves x {s1, s2}

    const float4* p = (const float4*)(inc + (size_t)row * L_LEN);
    float4 v0 = p[tid];                  // 256 threads x float4 = 1024 floats
    float4 v1 = p[tid + BLOCK];          // next 1024 floats

    float s1 = ((v0.x + v0.y) + (v0.z + v0.w)) + ((v1.x + v1.y) + (v1.z + v1.w));
    float s2 = ((v0.x * v0.x + v0.y * v0.y) + (v0.z * v0.z + v0.w * v0.w))
             + ((v1.x * v1.x + v1.y * v1.y) + (v1.z * v1.z + v1.w * v1.w));

#pragma unroll
    for (int off = 32; off > 0; off >>= 1) {
        s1 += __shfl_down(s1, off, 64);
        s2 += __shfl_down(s2, off, 64);
    }
    const int wave = tid >> 6;
    const int lane = tid & 63;
    if (lane == 0) {
        s_partial[wave * 2 + 0] = s1;
        s_partial[wave * 2 + 1] = s2;
    }
    __syncthreads();

    if (tid == 0) {
        const float S1 = (s_partial[0] + s_partial[2]) + (s_partial[4] + s_partial[6]);
        const float S2 = (s_partial[1] + s_partial[3]) + (s_partial[5] + s_partial[7]);
        const float A = ws[0];
        const float C = ws[1];
        out[row] = A * S2 / (S1 * S1) + C;
    }
}

extern "C" void kernel_launch(void* const* d_in, const int* in_sizes, int n_in,
                              void* d_out, int out_size, void* d_ws, size_t ws_size,
                              hipStream_t stream) {
    const float* inc = (const float*)d_in[0];   // [64, 32, 2048]
    const float* w1  = (const float*)d_in[1];
    const float* b1  = (const float*)d_in[2];
    const float* w2  = (const float*)d_in[3];
    const float* b2  = (const float*)d_in[4];
    const float* w3  = (const float*)d_in[5];
    const float* b3  = (const float*)d_in[6];
    const float* w4  = (const float*)d_in[7];
    const float* b4  = (const float*)d_in[8];
    float* out = (float*)d_out;                 // [64, 32] = 2048
    float* ws  = (float*)d_ws;

    fold_kernel<<<1, 64, 0, stream>>>(w1, b1, w2, b2, w3, b3, w4, b4, ws);
    reduce_kernel<<<out_size, BLOCK, 0, stream>>>(inc, ws, out);
}